// Round 10
// baseline (175.633 us; speedup 1.0000x reference)
//
#include <hip/hip_runtime.h>
#include <hip/hip_bf16.h>

// ---------------------------------------------------------------------------
// DropBlock fused dual-conv as implicit GEMM, 256^2 tile, BK=32.
// A: 4-slot LDS rotation (16 KB/slot, depth-3, 2 gll16/tile).
// B: DIRECT global->VGPR loads from L2-resident wt (no LDS), double-buffered.
// 1 barrier/tile; counted vmcnt/lgkmcnt; setprio around MFMA.
// Per-wave FIFO ledger (VMEM order: [.. A(t+2)x2, B(t)x4] entering P0(t)):
//   P0(t): BAR | ds av1(t) | gll16 A(t+3)x2 | VM(2) -> retires A(t+2)+B(t)
//          | LGKM(4) -> av0(t) ready | MM mh0: av0 x bv_par
//   P1(t): ds av0(t+1) | global bv_other = B(t+1) | LGKM(4) -> av1 ready
//          | MM mh1: av1 x bv_par
//   Publication: A(s) retired at VM(2)@P0(s-2), published BAR@P0(s-1),
//   first read P1(s-1). Slot-WAR: staging into (t-1)&3 issues after BAR@P0(t);
//   av1(t-1) drained at LGKM@P1(t-1), av0(t-1) at LGKM@P0(t-1) -- both before.
//   Prologue: B(0); A(0,1,2); VM(2) retires B0,A0,A1; BAR; ds av0(0).
//   Tails clamped (junk stages into rotating slot, never read; drained by
//   epilogue __syncthreads).
// ws: [0,4) dropped | [1024,+50176) sel | [65536,+29491200) xt bf16
//     [64][30][30][256] | [+2359296) wt bf16 [72*2][256 rows][32 k] UNSWIZZLED
// ---------------------------------------------------------------------------

typedef __bf16  bf16x8 __attribute__((ext_vector_type(8)));
typedef float   f32x4  __attribute__((ext_vector_type(4)));
typedef unsigned int u32;
typedef unsigned short u16;

#define XT_OFF     65536
#define WT_OFF     (65536 + 29491200)
#define SEL_OFF    1024

__device__ __forceinline__ u16 f2bf(float v) {
    u32 u = __float_as_uint(v);
    u32 r = (u + 0x7FFFu + ((u >> 16) & 1u)) >> 16;
    return (u16)r;
}

__device__ __forceinline__ void gll16(const void* g, void* l) {
    __builtin_amdgcn_global_load_lds(
        (const __attribute__((address_space(1))) u32*)g,
        (__attribute__((address_space(3))) u32*)l, 16, 0, 0);
}

// ---------------- fused prep: xt transform + wt blocks + mask --------------
__global__ void prep_kernel(const float* __restrict__ x,
                            const float* __restrict__ wl,
                            const float* __restrict__ wp,
                            const float* __restrict__ mu,
                            u16* __restrict__ xt, u16* __restrict__ wt,
                            unsigned char* __restrict__ sel,
                            int* __restrict__ dropped) {
    int b = blockIdx.x, tid = threadIdx.x;
    if (b < 1920) {                                   // ---- xt: 64*30 rows
        int n = b / 30, oh = b % 30;
        u16* row = xt + (size_t)(n * 30 + oh) * 30 * 256;
        if (oh == 0 || oh == 29) {                    // halo rows: full zero
            u32* r32 = (u32*)row;
            #pragma unroll
            for (int i = 0; i < 15; ++i) r32[i * 256 + tid] = 0;
            return;
        }
        int h = oh - 1;
        row[tid] = 0;
        row[29 * 256 + tid] = 0;
        const float* src = x + ((size_t)(n * 256 + tid) * 28 + h) * 28;
        float f[28];
        #pragma unroll
        for (int q = 0; q < 7; ++q) {
            float4 v = *(const float4*)(src + q * 4);
            f[q * 4 + 0] = v.x; f[q * 4 + 1] = v.y;
            f[q * 4 + 2] = v.z; f[q * 4 + 3] = v.w;
        }
        #pragma unroll
        for (int w = 0; w < 28; ++w)
            row[(1 + w) * 256 + tid] = f2bf(f[w]);
    } else if (b < 6528) {                            // ---- wt: plain blocks
        // block bb = t*2 + bn (t 0..71): [row 0..255][k 0..31] row-major
        int gid = (b - 1920) * 256 + tid;             // 1179648 exact
        int bb = gid >> 13;
        int e = gid & 8191;
        int t = bb >> 1, bnn = bb & 1;
        int kk = t >> 3;                              // tap 0..8
        int row = e >> 5, k = e & 31;
        int c = (t & 7) * 32 + k;
        const float* wsrc = bnn ? wp : wl;
        wt[gid] = f2bf(wsrc[((size_t)row * 256 + c) * 9 + kk]);
    } else {                                          // ---- mask + pooled sel
        int m = (b - 6528) * 256 + tid;               // 196*256 exact
        int n = m / 784, rem = m % 784;
        int h = rem / 28, w = rem % 28;
        const float g = (float)(0.1 / 49.0);
        const float* un = mu + n * 784;
        int p = 0;
        for (int dy = -3; dy <= 3; ++dy) {
            int hh = h + dy;
            if (hh < 0 || hh >= 28) continue;
            for (int dx = -3; dx <= 3; ++dx) {
                int ww = w + dx;
                if (ww < 0 || ww >= 28) continue;
                p |= (un[hh * 28 + ww] < g) ? 1 : 0;
            }
        }
        sel[m] = (unsigned char)p;
        unsigned long long bl = __ballot(p);
        if ((tid & 63) == 0) atomicAdd(dropped, __popcll(bl));
    }
}

// ---------------- implicit-GEMM conv + select + scale ----------------------
__global__ __launch_bounds__(512, 2)
void conv_kernel(const char* __restrict__ xt,    // bf16 padded NHWC (bytes)
                 const char* __restrict__ wt,    // bf16 weight blocks (bytes)
                 const unsigned char* __restrict__ sel,
                 const int* __restrict__ dropped,
                 float* __restrict__ out) {
    __shared__ char smem[66560];                  // 4 A-slots (64K) / ep (65K)
    const int tid = threadIdx.x;
    const int lb = (blockIdx.x & 7) * 49 + (blockIdx.x >> 3);  // XCD swizzle
    const int bm = lb >> 1;                  // 196 M-tiles of 256 positions
    const int bn = lb & 1;                   // 0 -> a, 1 -> b
    const int lane = tid & 63, wave = tid >> 6;
    const int lane15 = lane & 15, grp = lane >> 4;
    const int wm = wave >> 2, wn = wave & 3; // per-wave 128 x 64 output

    // --- A staging source bases; source-side swizzle folded in ---
    // gll16 #1: phys row tid>>2 (0..127); #2: row 128 + tid>>2
    long pb0, pb1;
    {
        int i = tid >> 2;
        int swz = ((tid & 3) ^ ((tid >> 3) & 3)) << 4;
        int m0 = bm * 256 + i;
        int n0 = m0 / 784, re0 = m0 % 784;
        pb0 = (long)(((n0 * 30 + re0 / 28 + 1) * 30 + (re0 % 28 + 1)) * 512 + swz);
        int m1 = m0 + 128;
        int n1 = m1 / 784, re1 = m1 % 784;
        pb1 = (long)(((n1 * 30 + re1 / 28 + 1) * 30 + (re1 % 28 + 1)) * 512 + swz);
    }

    f32x4 acc[8][4];
    #pragma unroll
    for (int i = 0; i < 8; ++i)
        #pragma unroll
        for (int j = 0; j < 4; ++j)
            acc[i][j] = (f32x4){0.f, 0.f, 0.f, 0.f};

    const int so  = (grp ^ ((lane15 >> 1) & 3)) << 4;    // A read swizzle
    const int arb = wm * 8192 + (lane15 << 6) + so;      // A byte base in slot
    const int bvo = ((wn * 64 + lane15) << 6) + (grp << 4);  // B lane offset

#define AON(TC) ((long)((TC) >> 3) / 3 * 15360 + (long)(((TC) >> 3) % 3) * 512 \
                 - 15872 + (long)(((TC) & 7) << 6))
#define DS_AV(dst, SLOT, MH) { _Pragma("unroll")                            \
        for (int fm = 0; fm < 4; ++fm)                                      \
            dst[fm] = *(const bf16x8*)(smem + ((SLOT) << 14) + (MH)*4096    \
                                       + arb + (fm << 10)); }
#define LD_BV(dst, TB) { const char* wb_ = wt + ((size_t)((TB)*2 + bn) << 14); \
        _Pragma("unroll")                                                   \
        for (int fn = 0; fn < 4; ++fn)                                      \
            dst[fn] = *(const bf16x8*)(wb_ + bvo + (fn << 10)); }
#define STG_A(TC, SLOT) { char* sd_ = smem + ((SLOT) << 14);                \
        const long ao_ = AON(TC);                                           \
        gll16(xt + pb0 + ao_, sd_ + (tid << 4));                            \
        gll16(xt + pb1 + ao_, sd_ + 8192 + (tid << 4)); }
#define MM(A0_, AV, BV) { __builtin_amdgcn_s_setprio(1);                    \
        _Pragma("unroll")                                                   \
        for (int fm = 0; fm < 4; ++fm)                                      \
            _Pragma("unroll")                                               \
            for (int fn = 0; fn < 4; ++fn)                                  \
                acc[(A0_)+fm][fn] = __builtin_amdgcn_mfma_f32_16x16x32_bf16( \
                    AV[fm], BV[fn], acc[(A0_)+fm][fn], 0, 0, 0);            \
        __builtin_amdgcn_s_setprio(0); }
#define LGKM(N) { asm volatile("s_waitcnt lgkmcnt(" #N ")" ::: "memory");   \
                  __builtin_amdgcn_sched_barrier(0); }
#define VM(N)   { asm volatile("s_waitcnt vmcnt(" #N ")" ::: "memory");     \
                  __builtin_amdgcn_sched_barrier(0); }
#define BAR     asm volatile("s_barrier" ::: "memory")

    bf16x8 av0[4], av1[4], bv0[4], bv1[4];

    // --- prologue ---
    LD_BV(bv0, 0);                  // B(0) -> regs   [4 vm ops]
    STG_A(0, 0);                    // A(0)           [2]
    STG_A(1, 1);                    // A(1)           [2]
    STG_A(2, 2);                    // A(2)           [2]
    VM(2);                          // retire B(0), A(0), A(1); A(2) in flight
    BAR;
    DS_AV(av0, 0, 0);               // av0(0)

    for (int u = 0; u < 36; ++u) {
        const int te = 2 * u, to = te + 1;
        // ---- tile te (uses bv0) ----
        {
            const int sc = te & 3, sn = to & 3, ss = (te + 3) & 3;
            int tc = te + 3; if (tc > 71) tc = 71;
            BAR;
            DS_AV(av1, sc, 1);
            STG_A(tc, ss);
            VM(2);                  // retire A(te+2) + B(te)
            LGKM(4);                // av0(te) ready
            MM(0, av0, bv0);
            // P1
            DS_AV(av0, sn, 0);      // av0(te+1)
            LD_BV(bv1, to);         // B(te+1)
            LGKM(4);                // av1(te) ready
            MM(4, av1, bv0);
        }
        // ---- tile to (uses bv1) ----
        {
            const int sc = to & 3, sn = (to + 1) & 3, ss = (to + 3) & 3;
            int tc = to + 3; if (tc > 71) tc = 71;
            int tb = to + 1; if (tb > 71) tb = 71;
            BAR;
            DS_AV(av1, sc, 1);
            STG_A(tc, ss);
            VM(2);                  // retire A(to+2) + B(to)
            LGKM(4);                // av0(to) ready
            MM(0, av0, bv1);
            // P1
            DS_AV(av0, sn, 0);      // av0(to+1) (junk at to=71, unused)
            LD_BV(bv0, tb);         // B(to+1) (clamped at end, unused)
            LGKM(4);                // av1(to) ready
            MM(4, av1, bv1);
        }
    }

    // --- epilogue: per-wave LDS transpose -> coalesced predicated stores ---
    float scale = 50176.0f / (float)(50176 - *dropped);
    float* ep = (float*)smem + wave * 2080;      // private [32][65] f32
    __syncthreads();    // full vm/lgkm drain (incl. junk ops) + barrier
    #pragma unroll
    for (int rr = 0; rr < 4; ++rr) {
        const int r2 = rr & 1;        // fn pair (32 channels)
        const int mh = rr >> 1;       // m half (64 positions)
        #pragma unroll
        for (int fm2 = 0; fm2 < 4; ++fm2)
            #pragma unroll
            for (int f2 = 0; f2 < 2; ++f2)
                #pragma unroll
                for (int j = 0; j < 4; ++j)
                    ep[(f2 * 16 + lane15) * 65 + fm2 * 16 + grp * 4 + j] =
                        acc[mh * 4 + fm2][r2 * 2 + f2][j];
        __syncthreads();
        {
            int p = bm * 256 + wm * 128 + mh * 64 + lane;
            int n = p / 784, rem = p % 784;
            unsigned char sv = sel[p];
            bool want = bn ? (sv != 0) : (sv == 0);
            size_t ob = (size_t)n * 200704 + rem;
            if (want) {
                #pragma unroll
                for (int ch = 0; ch < 32; ++ch)
                    out[ob + (size_t)(wn * 64 + r2 * 32 + ch) * 784] =
                        ep[ch * 65 + lane] * scale;
            }
        }
        __syncthreads();
    }
#undef AON
#undef DS_AV
#undef LD_BV
#undef STG_A
#undef MM
#undef LGKM
#undef VM
#undef BAR
}

// ---------------------------------------------------------------------------
extern "C" void kernel_launch(void* const* d_in, const int* in_sizes, int n_in,
                              void* d_out, int out_size, void* d_ws, size_t ws_size,
                              hipStream_t stream) {
    const float* x  = (const float*)d_in[0];
    const float* wl = (const float*)d_in[1];
    const float* wp = (const float*)d_in[2];
    const float* mu = (const float*)d_in[3];
    float* out = (float*)d_out;
    char* ws = (char*)d_ws;

    int* dropped = (int*)ws;
    unsigned char* sel = (unsigned char*)(ws + SEL_OFF);
    u16* xt = (u16*)(ws + XT_OFF);
    u16* wt = (u16*)(ws + WT_OFF);

    hipMemsetAsync(ws, 0, 4, stream);

    prep_kernel<<<6724, 256, 0, stream>>>(x, wl, wp, mu, xt, wt, sel, dropped);
    conv_kernel<<<392, 512, 0, stream>>>((const char*)xt, (const char*)wt,
                                         sel, dropped, out);
}

// Round 11
// 148.920 us; speedup vs baseline: 1.1794x; 1.1794x over previous
//
#include <hip/hip_runtime.h>
#include <hip/hip_bf16.h>

// ---------------------------------------------------------------------------
// DropBlock fused dual-conv as implicit GEMM. Tile 224x256 (M=224*224 exactly),
// BK=32, grid 448 = 8*56. 4-slot LDS rotation (30720 B/slot: A 14336 + B 16384),
// depth-3 prefetch, counted vmcnt/lgkmcnt, setprio (round-9 proven pipeline).
//   M = 50176, N = 512 (a|b), K = 2304; 72 K-tiles of 32; 2 phases/tile.
// Per-wave FIFO ledger (A(t+3)x2 staged @P0(t), B(t+3)x2 @P1(t)):
//   prologue: stage tiles 0,1,2 (12 ops); VM(8) retires tile 0; BAR;
//             read av0/bv(tile 0).
//   P0(t): ds av1(t) [3]; stage A(t+3); LGKM(3) -> av0/bv(t) ready;
//          MM16 mh0; VM(6) -> retires tile t+1; BAR (publishes t+1).
//   P1(t): ds av0(t+1) [4] + bv(t+1) [4]; stage B(t+3); LGKM(8) -> av1 ready;
//          MM12 mh1; BAR.
//   Slot WAR: stage into slot (t-1)&3 only after BAR end-of-(t-1). Tail t=70,71
//   peeled; clamped dup-stages land in dead slots; epilogue __syncthreads
//   (compiler emits vmcnt(0) lgkmcnt(0) + barrier) drains before LDS reuse.
// A staging: op1 rows 0..127 -> [0,8192); op2 rows 96..223 -> [6144,14336);
//   rows 96..127 double-written with IDENTICAL bytes (same swizzle) - benign.
// ws: [0,4) dropped | [1024,+50176) sel | [65536,+29491200) xt bf16
//     [64][30][30][256] | [+2359296) wt bf16 [72*2][256 rows][4 ps][8] swizzled
// ---------------------------------------------------------------------------

typedef __bf16  bf16x8 __attribute__((ext_vector_type(8)));
typedef float   f32x4  __attribute__((ext_vector_type(4)));
typedef unsigned int u32;
typedef unsigned short u16;

#define XT_OFF     65536
#define WT_OFF     (65536 + 29491200)
#define SEL_OFF    1024
#define SLOT       30720

__device__ __forceinline__ u16 f2bf(float v) {
    u32 u = __float_as_uint(v);
    u32 r = (u + 0x7FFFu + ((u >> 16) & 1u)) >> 16;
    return (u16)r;
}

__device__ __forceinline__ void gll16(const void* g, void* l) {
    __builtin_amdgcn_global_load_lds(
        (const __attribute__((address_space(1))) u32*)g,
        (__attribute__((address_space(3))) u32*)l, 16, 0, 0);
}

// ---------------- fused prep: xt transform + wt swizzle + mask -------------
__global__ void prep_kernel(const float* __restrict__ x,
                            const float* __restrict__ wl,
                            const float* __restrict__ wp,
                            const float* __restrict__ mu,
                            u16* __restrict__ xt, u16* __restrict__ wt,
                            unsigned char* __restrict__ sel,
                            int* __restrict__ dropped) {
    int b = blockIdx.x, tid = threadIdx.x;
    if (b < 1920) {                                   // ---- xt: 64*30 rows
        int n = b / 30, oh = b % 30;
        u16* row = xt + (size_t)(n * 30 + oh) * 30 * 256;
        if (oh == 0 || oh == 29) {                    // halo rows: full zero
            u32* r32 = (u32*)row;
            #pragma unroll
            for (int i = 0; i < 15; ++i) r32[i * 256 + tid] = 0;
            return;
        }
        int h = oh - 1;
        row[tid] = 0;
        row[29 * 256 + tid] = 0;
        const float* src = x + ((size_t)(n * 256 + tid) * 28 + h) * 28;
        float f[28];
        #pragma unroll
        for (int q = 0; q < 7; ++q) {
            float4 v = *(const float4*)(src + q * 4);
            f[q * 4 + 0] = v.x; f[q * 4 + 1] = v.y;
            f[q * 4 + 2] = v.z; f[q * 4 + 3] = v.w;
        }
        #pragma unroll
        for (int w = 0; w < 28; ++w)
            row[(1 + w) * 256 + tid] = f2bf(f[w]);
    } else if (b < 6528) {                            // ---- wt: BK=32 blocks
        // block bb = t*2 + bn (t 0..71): [row 0..255][ps 0..3][jj 0..7]
        // phys slot ps holds logical channels (ps ^ ((row>>1)&3))*8 + jj
        int gid = (b - 1920) * 256 + tid;             // 1179648 exact
        int bb = gid >> 13;
        int e = gid & 8191;
        int t = bb >> 1, bnn = bb & 1;
        int kk = t >> 3;                              // tap 0..8
        int row = e >> 5, r2 = e & 31;
        int ps = r2 >> 3, jj = r2 & 7;
        int c = (t & 7) * 32 + ((ps ^ ((row >> 1) & 3)) << 3) + jj;
        const float* wsrc = bnn ? wp : wl;
        wt[gid] = f2bf(wsrc[((size_t)row * 256 + c) * 9 + kk]);
    } else {                                          // ---- mask + pooled sel
        int m = (b - 6528) * 256 + tid;               // 196*256 exact
        int n = m / 784, rem = m % 784;
        int h = rem / 28, w = rem % 28;
        const float g = (float)(0.1 / 49.0);
        const float* un = mu + n * 784;
        int p = 0;
        for (int dy = -3; dy <= 3; ++dy) {
            int hh = h + dy;
            if (hh < 0 || hh >= 28) continue;
            for (int dx = -3; dx <= 3; ++dx) {
                int ww = w + dx;
                if (ww < 0 || ww >= 28) continue;
                p |= (un[hh * 28 + ww] < g) ? 1 : 0;
            }
        }
        sel[m] = (unsigned char)p;
        unsigned long long bl = __ballot(p);
        if ((tid & 63) == 0) atomicAdd(dropped, __popcll(bl));
    }
}

// ---------------- implicit-GEMM conv + select + scale ----------------------
__global__ __launch_bounds__(512, 2)
void conv_kernel(const char* __restrict__ xt,    // bf16 padded NHWC (bytes)
                 const char* __restrict__ wt,    // bf16 swizzled blocks (bytes)
                 const unsigned char* __restrict__ sel,
                 const int* __restrict__ dropped,
                 float* __restrict__ out) {
    __shared__ char smem[122880];                 // 4 slots x 30720
    const int tid = threadIdx.x;
    const int lb = (blockIdx.x & 7) * 56 + (blockIdx.x >> 3);  // 448 = 8*56
    const int bm = lb >> 1;                  // 224 M-tiles of 224 positions
    const int bn = lb & 1;                   // 0 -> a, 1 -> b
    const int lane = tid & 63, wave = tid >> 6;
    const int lane15 = lane & 15, grp = lane >> 4;
    const int wm = wave >> 2, wn = wave & 3; // per-wave 112 x 64 output

    // --- A staging source bases; source-side swizzle folded in ---
    long pb0, pb1;
    {
        int i = tid >> 2;
        int swz = ((tid & 3) ^ ((tid >> 3) & 3)) << 4;
        int m0 = bm * 224 + i;                       // rows 0..127
        int n0 = m0 / 784, re0 = m0 % 784;
        pb0 = (long)(((n0 * 30 + re0 / 28 + 1) * 30 + (re0 % 28 + 1)) * 512 + swz);
        int m1 = m0 + 96;                            // rows 96..223
        int n1 = m1 / 784, re1 = m1 % 784;
        pb1 = (long)(((n1 * 30 + re1 / 28 + 1) * 30 + (re1 % 28 + 1)) * 512 + swz);
    }

    f32x4 acc[7][4];
    #pragma unroll
    for (int i = 0; i < 7; ++i)
        #pragma unroll
        for (int j = 0; j < 4; ++j)
            acc[i][j] = (f32x4){0.f, 0.f, 0.f, 0.f};

    const int so  = (grp ^ ((lane15 >> 1) & 3)) << 4;    // read swizzle
    const int arb = wm * 7168 + (lane15 << 6) + so;      // A base in slot
    const int brb = 14336 + wn * 4096 + (lane15 << 6) + so;  // B base in slot

#define AON(TC) ((long)((TC) >> 3) / 3 * 15360 + (long)(((TC) >> 3) % 3) * 512 \
                 - 15872 + (long)(((TC) & 7) << 6))
#define DS_AV0(dst, SL) { const char* sb_ = smem + (SL) * SLOT;             \
        _Pragma("unroll")                                                   \
        for (int fm = 0; fm < 4; ++fm)                                      \
            dst[fm] = *(const bf16x8*)(sb_ + arb + (fm << 10)); }
#define DS_AV1(dst, SL) { const char* sb_ = smem + (SL) * SLOT + 4096;      \
        _Pragma("unroll")                                                   \
        for (int fm = 0; fm < 3; ++fm)                                      \
            dst[fm] = *(const bf16x8*)(sb_ + arb + (fm << 10)); }
#define DS_BV(dst, SL) { const char* sb_ = smem + (SL) * SLOT;              \
        _Pragma("unroll")                                                   \
        for (int fn = 0; fn < 4; ++fn)                                      \
            dst[fn] = *(const bf16x8*)(sb_ + brb + (fn << 10)); }
#define STG_A(TC, SL) { char* sd_ = smem + (SL) * SLOT;                     \
        const long ao_ = AON(TC);                                           \
        gll16(xt + pb0 + ao_, sd_ + (tid << 4));                            \
        gll16(xt + pb1 + ao_, sd_ + 6144 + (tid << 4)); }
#define STG_B(TC, SL) { char* sd_ = smem + (SL) * SLOT + 14336;             \
        const char* wb_ = wt + ((size_t)((TC) * 2 + bn) << 14);             \
        gll16(wb_ + (tid << 4), sd_ + (tid << 4));                          \
        gll16(wb_ + 8192 + (tid << 4), sd_ + 8192 + (tid << 4)); }
#define MM(A0_, NF, AV, BV) { __builtin_amdgcn_s_setprio(1);                \
        _Pragma("unroll")                                                   \
        for (int fm = 0; fm < (NF); ++fm)                                   \
            _Pragma("unroll")                                               \
            for (int fn = 0; fn < 4; ++fn)                                  \
                acc[(A0_)+fm][fn] = __builtin_amdgcn_mfma_f32_16x16x32_bf16( \
                    AV[fm], BV[fn], acc[(A0_)+fm][fn], 0, 0, 0);            \
        __builtin_amdgcn_s_setprio(0); }
#define LGKM(N) { asm volatile("s_waitcnt lgkmcnt(" #N ")" ::: "memory");   \
                  __builtin_amdgcn_sched_barrier(0); }
#define VM(N)   { asm volatile("s_waitcnt vmcnt(" #N ")" ::: "memory");     \
                  __builtin_amdgcn_sched_barrier(0); }
#define BAR     asm volatile("s_barrier" ::: "memory")

    bf16x8 av0[4], av1[3], bv0[4], bv1[4];

    // --- prologue: stage tiles 0,1,2 (A,A,B,B per tile) ---
    #pragma unroll
    for (int tt = 0; tt < 3; ++tt) {
        STG_A(tt, tt);
        STG_B(tt, tt);
    }
    VM(8);                          // retire tile 0 (12 -> 8)
    BAR;
    DS_AV0(av0, 0);
    DS_BV(bv0, 0);

    for (int u = 0; u < 35; ++u) {
        const int te = 2 * u, to = te + 1;
        // ---- tile te (even, bv0) ----
        {
            const int sc = te & 3, sn = to & 3, ss = (te + 3) & 3;
            int tc = te + 3; if (tc > 71) tc = 71;
            DS_AV1(av1, sc);
            STG_A(tc, ss);
            LGKM(3);                // av0/bv0(te) ready (prev-phase 8 reads)
            MM(0, 4, av0, bv0);
            VM(6);                  // retires tile te+1
            BAR;
            DS_AV0(av0, sn);
            DS_BV(bv1, sn);
            STG_B(tc, ss);
            LGKM(8);                // av1(te) ready
            MM(4, 3, av1, bv0);
            BAR;
        }
        // ---- tile to (odd, bv1) ----
        {
            const int sc = to & 3, sn = (to + 1) & 3, ss = (to + 3) & 3;
            int tc = to + 3; if (tc > 71) tc = 71;
            DS_AV1(av1, sc);
            STG_A(tc, ss);
            LGKM(3);
            MM(0, 4, av0, bv1);
            VM(6);                  // retires tile to+1
            BAR;
            DS_AV0(av0, sn);
            DS_BV(bv0, sn);
            STG_B(tc, ss);
            LGKM(8);
            MM(4, 3, av1, bv1);
            BAR;
        }
    }
    // ---- tail: tiles 70 (bv0), 71 (bv1) ----
    {
        // P0(70)
        DS_AV1(av1, 2);
        STG_A(71, 1);               // dup of 71 into dead slot 1
        LGKM(3);
        MM(0, 4, av0, bv0);
        VM(6);                      // retires tile 71 (real, slot 3)
        BAR;
        // P1(70)
        DS_AV0(av0, 3);
        DS_BV(bv1, 3);
        STG_B(71, 1);
        LGKM(8);
        MM(4, 3, av1, bv0);
        BAR;
        // P0(71)
        DS_AV1(av1, 3);
        LGKM(3);
        MM(0, 4, av0, bv1);
        // P1(71)
        LGKM(0);
        MM(4, 3, av1, bv1);
    }

    // --- epilogue: per-wave LDS transpose -> coalesced predicated stores ---
    float scale = 50176.0f / (float)(50176 - *dropped);
    float* ep = (float*)smem + wave * 2080;      // private [32][65] f32
    __syncthreads();    // full vm/lgkm drain (incl. dup gll16) + barrier
    #pragma unroll
    for (int rr = 0; rr < 4; ++rr) {
        const int r2 = rr & 1;        // fn pair (32 channels)
        const int mh = rr >> 1;       // m half: 0 -> 64 pos, 1 -> 48 pos
        const int nf = mh ? 3 : 4;
        for (int fm2 = 0; fm2 < nf; ++fm2)
            #pragma unroll
            for (int f2 = 0; f2 < 2; ++f2)
                #pragma unroll
                for (int j = 0; j < 4; ++j)
                    ep[(f2 * 16 + lane15) * 65 + fm2 * 16 + grp * 4 + j] =
                        acc[mh * 4 + fm2][r2 * 2 + f2][j];
        __syncthreads();
        if (mh == 0 || lane < 48) {
            int p = bm * 224 + wm * 112 + mh * 64 + lane;
            int n = p / 784, rem = p % 784;
            unsigned char sv = sel[p];
            bool want = bn ? (sv != 0) : (sv == 0);
            size_t ob = (size_t)n * 200704 + rem;
            if (want) {
                #pragma unroll
                for (int ch = 0; ch < 32; ++ch)
                    out[ob + (size_t)(wn * 64 + r2 * 32 + ch) * 784] =
                        ep[ch * 65 + lane] * scale;
            }
        }
        __syncthreads();
    }
#undef AON
#undef DS_AV0
#undef DS_AV1
#undef DS_BV
#undef STG_A
#undef STG_B
#undef MM
#undef LGKM
#undef VM
#undef BAR
}

// ---------------------------------------------------------------------------
extern "C" void kernel_launch(void* const* d_in, const int* in_sizes, int n_in,
                              void* d_out, int out_size, void* d_ws, size_t ws_size,
                              hipStream_t stream) {
    const float* x  = (const float*)d_in[0];
    const float* wl = (const float*)d_in[1];
    const float* wp = (const float*)d_in[2];
    const float* mu = (const float*)d_in[3];
    float* out = (float*)d_out;
    char* ws = (char*)d_ws;

    int* dropped = (int*)ws;
    unsigned char* sel = (unsigned char*)(ws + SEL_OFF);
    u16* xt = (u16*)(ws + XT_OFF);
    u16* wt = (u16*)(ws + WT_OFF);

    hipMemsetAsync(ws, 0, 4, stream);

    prep_kernel<<<6724, 256, 0, stream>>>(x, wl, wp, mu, xt, wt, sel, dropped);
    conv_kernel<<<448, 512, 0, stream>>>((const char*)xt, (const char*)wt,
                                         sel, dropped, out);
}